// Round 25
// baseline (53.138 us; speedup 1.0000x reference)
//
#include <hip/hip_runtime.h>
#include <math.h>

#define NB       1025
#define M        1024      // half-length complex FFT size
#define FFTN     2048
#define HOP      512
#define NFRAMES  4000
#define BATCH    4
#define OUT_T    2047488   // (F-1)*hop + N - 2*half
#define NPAIR    251       // 16-hop combined regions per batch (501 regions + phantom)
#define NWG      (BATCH * NPAIR)   // 1004 = 3.92 blocks/CU
#define CHOPS    16        // hops per block
#define PI_F     3.14159265358979323846f

__device__ __forceinline__ float2 cmul(float2 a, float2 b) {
    return make_float2(a.x*b.x - a.y*b.y, a.x*b.y + a.y*b.x);
}
__device__ __forceinline__ float4 cmul4(float4 v, float2 w) {
    return make_float4(v.x*w.x - v.y*w.y, v.x*w.y + v.y*w.x,
                       v.z*w.x - v.w*w.y, v.z*w.y + v.w*w.x);
}
__device__ __forceinline__ float4 f4add(float4 a, float4 b){ return make_float4(a.x+b.x, a.y+b.y, a.z+b.z, a.w+b.w); }
__device__ __forceinline__ float4 f4sub(float4 a, float4 b){ return make_float4(a.x-b.x, a.y-b.y, a.z-b.z, a.w-b.w); }
__device__ __forceinline__ float4 f4addi(float4 a, float4 b){ return make_float4(a.x-b.y, a.y+b.x, a.z-b.w, a.w+b.z); } // a + i*b per half
__device__ __forceinline__ float4 f4subi(float4 a, float4 b){ return make_float4(a.x+b.y, a.y-b.x, a.z+b.w, a.w-b.z); } // a - i*b per half

// float4 bank-group swizzle (R14-verified: conflicts 4.2M -> 1.5M)
__device__ __forceinline__ int SW4(int i) { return i ^ ((i >> 3) & 7); }

// window_sumsquare at trimmed position p (boundary path, <=4 terms)
__device__ __forceinline__ float wsq_at(int p) {
    int u  = p + FFTN / 2;
    int fm = u >> 9;
    int n0 = u & 511;
    float wsq = 0.f;
    #pragma unroll
    for (int jj = 0; jj < 4; ++jj) {
        int fr = fm - jj;
        if (fr >= 0 && fr < NFRAMES) {
            int n = n0 + (jj << 9);
            float sw = __sinf((PI_F / (float)FFTN) * (float)n);
            float w  = sw * sw;
            wsq += w * w;
        }
    }
    const float tiny = 1.17549435e-38f;
    return (wsq > tiny) ? wsq : 1.0f;
}
__device__ __forceinline__ float invw_at(int p, bool edge) {
    if (edge && (p < 512 || p >= OUT_T - 512)) return 1.0f / wsq_at(p);
    return (2.0f / 3.0f);
}

// Out-of-place Stockham stage on paired-frame float4 elements.
// Twiddles w1,w2,w3 all hoisted (no per-call cmul recompute).
template<int ST>
__device__ __forceinline__ void stage4x(const float4* __restrict__ src,
                                        float4* __restrict__ dst, int j,
                                        float2 w1, float2 w2, float2 w3) {
    const int Ns = 1 << (2 * ST);
    float4 v0 = src[SW4(j)];
    float4 v1 = src[SW4(j + 256)];
    float4 v2 = src[SW4(j + 512)];
    float4 v3 = src[SW4(j + 768)];
    v1 = cmul4(v1, w1); v2 = cmul4(v2, w2); v3 = cmul4(v3, w3);
    float4 t0 = f4add(v0, v2), t1 = f4sub(v0, v2);
    float4 t2 = f4add(v1, v3), t3 = f4sub(v1, v3);
    int jm = j & (Ns - 1);
    int idxD = ((j >> (2 * ST)) << (2 * ST + 2)) + jm;
    dst[SW4(idxD         )] = f4add(t0, t2);
    dst[SW4(idxD +     Ns)] = f4addi(t1, t3);
    dst[SW4(idxD + 2 * Ns)] = f4sub(t0, t2);
    dst[SW4(idxD + 3 * Ns)] = f4subi(t1, t3);
}

__device__ __forceinline__ void load_spec(const float* __restrict__ sr,
                                          const float* __restrict__ si,
                                          int b, int f, int j,
                                          float* car, float* cai,
                                          float* cbr, float* cbi) {
    const size_t fb = ((size_t)b * NFRAMES + f) * NB;
    const float* __restrict__ xr = sr + fb;
    const float* __restrict__ xi = si + fb;
    #pragma unroll
    for (int kk = 0; kk < 4; ++kk) {
        int k  = j + kk * 256;
        int mk = M - k;
        car[kk] = xr[k];  cai[kk] = xi[k];
        cbr[kk] = xr[mk]; cbi[kk] = xi[mk];
    }
}

// Hermitian pack (both frames) + Stockham stage 0 fused -> float4 LDS.
__device__ __forceinline__ void pack2_st0(float4* __restrict__ dst, int j,
                                          const float2* twp,
                                          const float* a1r, const float* a1i,
                                          const float* b1r, const float* b1i,
                                          const float* a2r, const float* a2i,
                                          const float* b2r, const float* b2i) {
    float4 z[4];
    #pragma unroll
    for (int kk = 0; kk < 4; ++kk) {
        float ar = a1r[kk], ai = a1i[kk], br = b1r[kk], bi = b1i[kk];
        float cr = a2r[kk], ci = a2i[kk], dr = b2r[kk], di = b2i[kk];
        if (kk == 0 && j == 0) { ai = 0.f; bi = 0.f; ci = 0.f; di = 0.f; }
        float2 t = twp[kk];
        float Er = 0.5f*(ar+br), Ei = 0.5f*(ai-bi), Dr = 0.5f*(ar-br), Di = 0.5f*(ai+bi);
        float Or = Dr*t.x - Di*t.y, Oi = Dr*t.y + Di*t.x;
        float Fr = 0.5f*(cr+dr), Fi = 0.5f*(ci-di), Gr = 0.5f*(cr-dr), Gi = 0.5f*(ci+di);
        float Pr = Gr*t.x - Gi*t.y, Pi = Gr*t.y + Gi*t.x;
        z[kk] = make_float4(Er - Oi, Ei + Or, Fr - Pi, Fi + Pr);
    }
    float4 t0 = f4add(z[0], z[2]), t1 = f4sub(z[0], z[2]);
    float4 t2 = f4add(z[1], z[3]), t3 = f4sub(z[1], z[3]);
    dst[SW4(4*j    )] = f4add(t0, t2);
    dst[SW4(4*j + 1)] = f4addi(t1, t3);
    dst[SW4(4*j + 2)] = f4sub(t0, t2);
    dst[SW4(4*j + 3)] = f4subi(t1, t3);
}

// Two regions per block with a UNIFIED 16-hop register accumulator (R22
// champion) + fully hoisted stage twiddles (saves ~48 VALU/iteration).
__global__ __launch_bounds__(256) void istft_pair_kernel(
    const float* __restrict__ sr, const float* __restrict__ si,
    float* __restrict__ out)
{
    __shared__ float4 buf0[M];   // 16 KB
    __shared__ float4 buf1[M];   // 16 KB

    // T1 bijective XCD swizzle (NWG=1004, 8 XCDs)
    int blk;
    {
        const int o   = blockIdx.x;
        const int xcd = o & 7, k = o >> 3;
        const int q = NWG / 8, r = NWG % 8;   // 125, 4
        blk = (xcd < r ? xcd * (q + 1) : r * (q + 1) + (xcd - r) * q) + k;
    }

    const int b    = blk / NPAIR;
    const int pr   = blk - b * NPAIR;
    const int regA = 2 * pr;
    const int s0hA = regA * 8;           // combined region = hops s0hA..s0hA+15
    const int j    = threadIdx.x;
    const bool edge = (regA == 0) || (regA == 500);

    // ---- per-block precompute ----
    float2 tw_pack[4];
    #pragma unroll
    for (int kk = 0; kk < 4; ++kk) {
        int k = j + kk * 256;
        float s, c;
        __sincosf(PI_F * (float)k * (1.0f / (float)M), &s, &c);
        tw_pack[kk] = make_float2(c, s);
    }
    float2 w1s[4], w2s[4], w3s[4];       // all three stage twiddles hoisted
    #pragma unroll
    for (int st = 1; st <= 4; ++st) {
        int Ns = 1 << (2 * st);
        int jm = j & (Ns - 1);
        float ang = (0.5f * PI_F / (float)Ns) * (float)jm;
        float s1, c1;
        __sincosf(ang, &s1, &c1);
        float2 w1 = make_float2(c1, s1);
        w1s[st-1] = w1;
        w2s[st-1] = cmul(w1, w1);
        w3s[st-1] = cmul(w2s[st-1], w1);
    }
    float wreg[4][2];
    #pragma unroll
    for (int q = 0; q < 4; ++q) {
        int n = j + q * 256;
        #pragma unroll
        for (int h = 0; h < 2; ++h) {
            int t = 2 * n + h;
            float swv = __sinf((PI_F / (float)FFTN) * (float)t);
            wreg[q][h] = swv * swv * (1.0f / 1024.0f);
        }
    }

    // unified accumulator: thread j owns combined float2 slots {256*s + j}
    float2 Acc[CHOPS];
    #pragma unroll
    for (int s = 0; s < CHOPS; ++s) Acc[s] = make_float2(0.f, 0.f);

    const int fbase = s0hA - 3;          // frame slot it2 = f - fbase, 0..18

    #pragma unroll
    for (int t = 0; t < 10; ++t) {
        const int fA = fbase + 2 * t;    // slot 2t   -> s = 2t-3+q
        const int fB = fA + 1;           // slot 2t+1 -> s = 2t-2+q
        const bool vA = (fA >= 0) && (fA < NFRAMES);
        const bool vB = (t < 9) && (fB >= 0) && (fB < NFRAMES);  // t=9 B phantom
        if (!vA && !vB) continue;        // block-uniform skip

        int fAc = fA < 0 ? 0 : (fA > NFRAMES-1 ? NFRAMES-1 : fA);
        int fBc = fB < 0 ? 0 : (fB > NFRAMES-1 ? NFRAMES-1 : fB);

        float a1r[4], a1i[4], b1r[4], b1i[4];
        float a2r[4], a2i[4], b2r[4], b2i[4];
        load_spec(sr, si, b, fAc, j, a1r, a1i, b1r, b1i);
        load_spec(sr, si, b, fBc, j, a2r, a2i, b2r, b2i);

        pack2_st0(buf0, j, tw_pack, a1r, a1i, b1r, b1i, a2r, a2i, b2r, b2i);
        __syncthreads();
        stage4x<1>(buf0, buf1, j, w1s[0], w2s[0], w3s[0]);
        __syncthreads();
        stage4x<2>(buf1, buf0, j, w1s[1], w2s[1], w3s[1]);
        __syncthreads();
        stage4x<3>(buf0, buf1, j, w1s[2], w2s[2], w3s[2]);
        __syncthreads();

        // ---- stage 4 in registers + masked windowed accumulate ----
        {
            float4 v0 = buf1[SW4(j)];
            float4 v1 = buf1[SW4(j + 256)];
            float4 v2 = buf1[SW4(j + 512)];
            float4 v3 = buf1[SW4(j + 768)];
            v1 = cmul4(v1, w1s[3]); v2 = cmul4(v2, w2s[3]); v3 = cmul4(v3, w3s[3]);
            float4 t0 = f4add(v0, v2), t1 = f4sub(v0, v2);
            float4 t2 = f4add(v1, v3), t3 = f4sub(v1, v3);
            float4 g[4];
            g[0] = f4add(t0, t2);    // n = j
            g[1] = f4addi(t1, t3);   // n = j+256
            g[2] = f4sub(t0, t2);    // n = j+512
            g[3] = f4subi(t1, t3);   // n = j+768
            if (vA) {
                #pragma unroll
                for (int q = 0; q < 4; ++q) {
                    const int s = 2 * t - 3 + q;       // compile-time
                    if (s >= 0 && s < CHOPS) {
                        Acc[s].x += g[q].x * wreg[q][0];
                        Acc[s].y += g[q].y * wreg[q][1];
                    }
                }
            }
            if (vB) {
                #pragma unroll
                for (int q = 0; q < 4; ++q) {
                    const int s = 2 * t - 2 + q;       // compile-time
                    if (s >= 0 && s < CHOPS) {
                        Acc[s].x += g[q].z * wreg[q][0];
                        Acc[s].y += g[q].w * wreg[q][1];
                    }
                }
            }
        }
        // NO trailing barrier (R16-verified ping-pong argument).
    }

    // ---- epilogue: divide by wsq, coalesced single store per sample ----
    float* outb = out + (size_t)b * OUT_T;
    const int base_u = s0hA * HOP;
    #pragma unroll
    for (int s = 0; s < CHOPS; ++s) {
        int i2 = j + 256 * s;
        int p0 = base_u + 2 * i2 - FFTN / 2;
        int p1 = p0 + 1;
        if ((unsigned)p0 < (unsigned)OUT_T) outb[p0] = Acc[s].x * invw_at(p0, edge);
        if ((unsigned)p1 < (unsigned)OUT_T) outb[p1] = Acc[s].y * invw_at(p1, edge);
    }
}

extern "C" void kernel_launch(void* const* d_in, const int* in_sizes, int n_in,
                              void* d_out, int out_size, void* d_ws, size_t ws_size,
                              hipStream_t stream) {
    const float* sr = (const float*)d_in[0];
    const float* si = (const float*)d_in[1];
    float* out = (float*)d_out;
    istft_pair_kernel<<<NWG, 256, 0, stream>>>(sr, si, out);
}

// Round 26
// 49.754 us; speedup vs baseline: 1.0680x; 1.0680x over previous
//
#include <hip/hip_runtime.h>
#include <math.h>

#define NB       1025
#define M        1024      // half-length complex FFT size
#define FFTN     2048
#define HOP      512
#define NFRAMES  4000
#define BATCH    4
#define OUT_T    2047488   // (F-1)*hop + N - 2*half
#define R_HOPS   8
#define NPAIR    251       // pairs/batch; pair p -> regions 2p, 2p+1 (501 = phantom)
#define NWG      (BATCH * NPAIR)   // 1004
#define CHOPS    16        // combined region hops (2 regions)
#define PI_F     3.14159265358979323846f

__device__ __forceinline__ float2 cmul(float2 a, float2 b) {
    return make_float2(a.x*b.x - a.y*b.y, a.x*b.y + a.y*b.x);
}
__device__ __forceinline__ float4 cmul4(float4 v, float2 w) {
    return make_float4(v.x*w.x - v.y*w.y, v.x*w.y + v.y*w.x,
                       v.z*w.x - v.w*w.y, v.z*w.y + v.w*w.x);
}
__device__ __forceinline__ float4 f4add(float4 a, float4 b){ return make_float4(a.x+b.x, a.y+b.y, a.z+b.z, a.w+b.w); }
__device__ __forceinline__ float4 f4sub(float4 a, float4 b){ return make_float4(a.x-b.x, a.y-b.y, a.z-b.z, a.w-b.w); }
__device__ __forceinline__ float4 f4addi(float4 a, float4 b){ return make_float4(a.x-b.y, a.y+b.x, a.z-b.w, a.w+b.z); } // a + i*b per half
__device__ __forceinline__ float4 f4subi(float4 a, float4 b){ return make_float4(a.x+b.y, a.y-b.x, a.z+b.w, a.w-b.z); } // a - i*b per half

// float4 bank-group swizzle (R14-verified: conflicts 4.2M -> 1.5M)
__device__ __forceinline__ int SW4(int i) { return i ^ ((i >> 3) & 7); }

// window_sumsquare at trimmed position p (boundary path, <=4 terms)
__device__ __forceinline__ float wsq_at(int p) {
    int u  = p + FFTN / 2;
    int fm = u >> 9;
    int n0 = u & 511;
    float wsq = 0.f;
    #pragma unroll
    for (int jj = 0; jj < 4; ++jj) {
        int fr = fm - jj;
        if (fr >= 0 && fr < NFRAMES) {
            int n = n0 + (jj << 9);
            float sw = __sinf((PI_F / (float)FFTN) * (float)n);
            float w  = sw * sw;
            wsq += w * w;
        }
    }
    const float tiny = 1.17549435e-38f;
    return (wsq > tiny) ? wsq : 1.0f;
}
__device__ __forceinline__ float invw_at(int p, bool edge) {
    if (edge && (p < 512 || p >= OUT_T - 512)) return 1.0f / wsq_at(p);
    return (2.0f / 3.0f);
}

// Out-of-place Stockham stage on paired-frame float4 elements.
template<int ST>
__device__ __forceinline__ void stage4x(const float4* __restrict__ src,
                                        float4* __restrict__ dst, int j, float2 w1) {
    const int Ns = 1 << (2 * ST);
    float4 v0 = src[SW4(j)];
    float4 v1 = src[SW4(j + 256)];
    float4 v2 = src[SW4(j + 512)];
    float4 v3 = src[SW4(j + 768)];
    float2 w2 = cmul(w1, w1);
    float2 w3 = cmul(w2, w1);
    v1 = cmul4(v1, w1); v2 = cmul4(v2, w2); v3 = cmul4(v3, w3);
    float4 t0 = f4add(v0, v2), t1 = f4sub(v0, v2);
    float4 t2 = f4add(v1, v3), t3 = f4sub(v1, v3);
    int jm = j & (Ns - 1);
    int idxD = ((j >> (2 * ST)) << (2 * ST + 2)) + jm;
    dst[SW4(idxD         )] = f4add(t0, t2);
    dst[SW4(idxD +     Ns)] = f4addi(t1, t3);
    dst[SW4(idxD + 2 * Ns)] = f4sub(t0, t2);
    dst[SW4(idxD + 3 * Ns)] = f4subi(t1, t3);
}

__device__ __forceinline__ void load_spec(const float* __restrict__ sr,
                                          const float* __restrict__ si,
                                          int b, int f, int j,
                                          float* car, float* cai,
                                          float* cbr, float* cbi) {
    const size_t fb = ((size_t)b * NFRAMES + f) * NB;
    const float* __restrict__ xr = sr + fb;
    const float* __restrict__ xi = si + fb;
    #pragma unroll
    for (int kk = 0; kk < 4; ++kk) {
        int k  = j + kk * 256;
        int mk = M - k;
        car[kk] = xr[k];  cai[kk] = xi[k];
        cbr[kk] = xr[mk]; cbi[kk] = xi[mk];
    }
}

// Hermitian pack (both frames) + Stockham stage 0 fused -> float4 LDS.
__device__ __forceinline__ void pack2_st0(float4* __restrict__ dst, int j,
                                          const float2* twp,
                                          const float* a1r, const float* a1i,
                                          const float* b1r, const float* b1i,
                                          const float* a2r, const float* a2i,
                                          const float* b2r, const float* b2i) {
    float4 z[4];
    #pragma unroll
    for (int kk = 0; kk < 4; ++kk) {
        float ar = a1r[kk], ai = a1i[kk], br = b1r[kk], bi = b1i[kk];
        float cr = a2r[kk], ci = a2i[kk], dr = b2r[kk], di = b2i[kk];
        if (kk == 0 && j == 0) { ai = 0.f; bi = 0.f; ci = 0.f; di = 0.f; }
        float2 t = twp[kk];
        float Er = 0.5f*(ar+br), Ei = 0.5f*(ai-bi), Dr = 0.5f*(ar-br), Di = 0.5f*(ai+bi);
        float Or = Dr*t.x - Di*t.y, Oi = Dr*t.y + Di*t.x;
        float Fr = 0.5f*(cr+dr), Fi = 0.5f*(ci-di), Gr = 0.5f*(cr-dr), Gi = 0.5f*(ci+di);
        float Pr = Gr*t.x - Gi*t.y, Pi = Gr*t.y + Gi*t.x;
        z[kk] = make_float4(Er - Oi, Ei + Or, Fr - Pi, Fi + Pr);
    }
    float4 t0 = f4add(z[0], z[2]), t1 = f4sub(z[0], z[2]);
    float4 t2 = f4add(z[1], z[3]), t3 = f4sub(z[1], z[3]);
    dst[SW4(4*j    )] = f4add(t0, t2);
    dst[SW4(4*j + 1)] = f4addi(t1, t3);
    dst[SW4(4*j + 2)] = f4sub(t0, t2);
    dst[SW4(4*j + 3)] = f4subi(t1, t3);
}

// Two regions per block with a UNIFIED 16-hop register accumulator:
// the 19 distinct frames are FFT'd exactly once each (10 float4-paired
// iterations, last B-slot phantom) — removes the 3 duplicate frame FFTs
// the split-accumulator version paid per block.
__global__ __launch_bounds__(256) void istft_pair_kernel(
    const float* __restrict__ sr, const float* __restrict__ si,
    float* __restrict__ out)
{
    __shared__ float4 buf0[M];   // 16 KB
    __shared__ float4 buf1[M];   // 16 KB

    // T1 bijective XCD swizzle (neutral but kept; NWG=1004, 8 XCDs)
    int blk;
    {
        const int o   = blockIdx.x;
        const int xcd = o & 7, k = o >> 3;
        const int q = NWG / 8, r = NWG % 8;   // 125, 4
        blk = (xcd < r ? xcd * (q + 1) : r * (q + 1) + (xcd - r) * q) + k;
    }

    const int b    = blk / NPAIR;
    const int pr   = blk - b * NPAIR;
    const int regA = 2 * pr;
    const int s0hA = regA * R_HOPS;      // combined region = hops s0hA..s0hA+15
    const int j    = threadIdx.x;
    const bool edge = (regA == 0) || (regA == 500);  // blocks containing wsq boundary

    // ---- per-block precompute ----
    float2 tw_pack[4];
    #pragma unroll
    for (int kk = 0; kk < 4; ++kk) {
        int k = j + kk * 256;
        float s, c;
        __sincosf(PI_F * (float)k * (1.0f / (float)M), &s, &c);
        tw_pack[kk] = make_float2(c, s);
    }
    float2 w1s[4];
    #pragma unroll
    for (int st = 1; st <= 4; ++st) {
        int Ns = 1 << (2 * st);
        int jm = j & (Ns - 1);
        float ang = (0.5f * PI_F / (float)Ns) * (float)jm;
        float s1, c1;
        __sincosf(ang, &s1, &c1);
        w1s[st-1] = make_float2(c1, s1);
    }
    float wreg[4][2];
    #pragma unroll
    for (int q = 0; q < 4; ++q) {
        int n = j + q * 256;
        #pragma unroll
        for (int h = 0; h < 2; ++h) {
            int t = 2 * n + h;
            float swv = __sinf((PI_F / (float)FFTN) * (float)t);
            wreg[q][h] = swv * swv * (1.0f / 1024.0f);
        }
    }

    // unified accumulator: thread j owns combined float2 slots {256*s + j}
    float2 Acc[CHOPS];
    #pragma unroll
    for (int s = 0; s < CHOPS; ++s) Acc[s] = make_float2(0.f, 0.f);

    const int fbase = s0hA - 3;          // frame slot it2 = f - fbase, 0..18

    #pragma unroll
    for (int t = 0; t < 10; ++t) {
        const int fA = fbase + 2 * t;    // slot it2 = 2t   -> s = 2t-3+q
        const int fB = fA + 1;           // slot it2 = 2t+1 -> s = 2t-2+q
        const bool vA = (fA >= 0) && (fA < NFRAMES);
        const bool vB = (t < 9) && (fB >= 0) && (fB < NFRAMES);  // t=9 B phantom
        if (!vA && !vB) continue;        // block-uniform skip

        int fAc = fA < 0 ? 0 : (fA > NFRAMES-1 ? NFRAMES-1 : fA);
        int fBc = fB < 0 ? 0 : (fB > NFRAMES-1 ? NFRAMES-1 : fB);

        float a1r[4], a1i[4], b1r[4], b1i[4];
        float a2r[4], a2i[4], b2r[4], b2i[4];
        load_spec(sr, si, b, fAc, j, a1r, a1i, b1r, b1i);
        load_spec(sr, si, b, fBc, j, a2r, a2i, b2r, b2i);

        pack2_st0(buf0, j, tw_pack, a1r, a1i, b1r, b1i, a2r, a2i, b2r, b2i);
        __syncthreads();
        stage4x<1>(buf0, buf1, j, w1s[0]);
        __syncthreads();
        stage4x<2>(buf1, buf0, j, w1s[1]);
        __syncthreads();
        stage4x<3>(buf0, buf1, j, w1s[2]);
        __syncthreads();

        // ---- stage 4 in registers + masked windowed accumulate ----
        {
            float4 v0 = buf1[SW4(j)];
            float4 v1 = buf1[SW4(j + 256)];
            float4 v2 = buf1[SW4(j + 512)];
            float4 v3 = buf1[SW4(j + 768)];
            float2 w1 = w1s[3];
            float2 w2 = cmul(w1, w1);
            float2 w3 = cmul(w2, w1);
            v1 = cmul4(v1, w1); v2 = cmul4(v2, w2); v3 = cmul4(v3, w3);
            float4 t0 = f4add(v0, v2), t1 = f4sub(v0, v2);
            float4 t2 = f4add(v1, v3), t3 = f4sub(v1, v3);
            float4 g[4];
            g[0] = f4add(t0, t2);    // n = j
            g[1] = f4addi(t1, t3);   // n = j+256
            g[2] = f4sub(t0, t2);    // n = j+512
            g[3] = f4subi(t1, t3);   // n = j+768
            if (vA) {
                #pragma unroll
                for (int q = 0; q < 4; ++q) {
                    const int s = 2 * t - 3 + q;       // compile-time
                    if (s >= 0 && s < CHOPS) {
                        Acc[s].x += g[q].x * wreg[q][0];
                        Acc[s].y += g[q].y * wreg[q][1];
                    }
                }
            }
            if (vB) {
                #pragma unroll
                for (int q = 0; q < 4; ++q) {
                    const int s = 2 * t - 2 + q;       // compile-time
                    if (s >= 0 && s < CHOPS) {
                        Acc[s].x += g[q].z * wreg[q][0];
                        Acc[s].y += g[q].w * wreg[q][1];
                    }
                }
            }
        }
        // NO trailing barrier (R16-verified ping-pong argument): next pack
        // writes buf0 only — its last readers (stage3) are behind the stage3
        // barrier; st4's buf1 reads complete before this thread reaches the
        // next pack barrier, which precedes stage1(t+1)'s buf1 writes.
    }

    // ---- epilogue: divide by wsq, coalesced single store per sample ----
    float* outb = out + (size_t)b * OUT_T;
    const int base_u = s0hA * HOP;
    #pragma unroll
    for (int s = 0; s < CHOPS; ++s) {
        int i2 = j + 256 * s;
        int p0 = base_u + 2 * i2 - FFTN / 2;
        int p1 = p0 + 1;
        if ((unsigned)p0 < (unsigned)OUT_T) outb[p0] = Acc[s].x * invw_at(p0, edge);
        if ((unsigned)p1 < (unsigned)OUT_T) outb[p1] = Acc[s].y * invw_at(p1, edge);
    }
}

extern "C" void kernel_launch(void* const* d_in, const int* in_sizes, int n_in,
                              void* d_out, int out_size, void* d_ws, size_t ws_size,
                              hipStream_t stream) {
    const float* sr = (const float*)d_in[0];
    const float* si = (const float*)d_in[1];
    float* out = (float*)d_out;
    istft_pair_kernel<<<NWG, 256, 0, stream>>>(sr, si, out);
}